// Round 10
// baseline (76.328 us; speedup 1.0000x reference)
//
#include <hip/hip_runtime.h>

// NewSupConLoss: B=512, L=20, D=128. Symmetric Gram (triangle only), fused
// exp/rowsum, zero atomics. Units = (32-row strip R, col-class c>=class(R)),
// 3360 single-wave blocks; per-unit slices of 16 cols, depth-2 staged
// (3x4KB LDS, vmcnt(8)). Row credits -> Pr (f32); mirror col credits ->
// Pm (bf16, zero-init, single writer). Diagonal 32x32 blocks computed fully
// with i==j masked, row-credit only.

#define NB 512
#define NL 20
#define NROW (NB * NL)            // 10240
#define FBYTES (NROW * 256)       // 2,621,440
#define PM_ELEMS (320 * 10240)    // 20 classes x 16 strips x 10240 cols
#define SCALE 4.5398160f          // sqrt(log2(e)/0.07); dot feeds exp2 directly
#define TEMP_INV 14.285714285714286f

typedef float f32x4 __attribute__((ext_vector_type(4)));
typedef short short8 __attribute__((ext_vector_type(8)));
typedef unsigned short ushort4v __attribute__((ext_vector_type(4)));
typedef unsigned int uint4v __attribute__((ext_vector_type(4)));

static __device__ __forceinline__ unsigned short f2bf(float x) {
  unsigned int b = __float_as_uint(x);
  b += 0x7FFFu + ((b >> 16) & 1u);
  return (unsigned short)(b >> 16);
}
static __device__ __forceinline__ float bf2f(unsigned short u) {
  return __uint_as_float(((unsigned int)u) << 16);
}
static __device__ __forceinline__ float fexp2(float x) {
#if __has_builtin(__builtin_amdgcn_exp2f)
  return __builtin_amdgcn_exp2f(x);
#else
  return exp2f(x);
#endif
}

// Blocks [0,1280): fp32 -> bf16 rows a=l*512+i, scaled, XOR-swizzled.
// Blocks [1280,1600): gp[c][grp][d] partial g-sums (16 independent loads/thread).
// Blocks [1600,3200): zero Pm (16B/thread).
__global__ __launch_bounds__(256) void k_prep(const float* __restrict__ feat,
                                              const int* __restrict__ labels,
                                              unsigned char* __restrict__ fswz,
                                              float* __restrict__ gp,
                                              unsigned short* __restrict__ Pm) {
  const int b = blockIdx.x;
  if (b < 1280) {
    int t = b * 256 + threadIdx.x;   // [0, 327680)
    int q = t & 31;
    int a = t >> 5;
    int l = a >> 9;
    int i = a & 511;
    const float* src = feat + (size_t)i * (NL * 128) + l * 128 + q * 4;
    float4 v = *(const float4*)src;
    ushort4v u;
    u.x = f2bf(v.x * SCALE); u.y = f2bf(v.y * SCALE);
    u.z = f2bf(v.z * SCALE); u.w = f2bf(v.w * SCALE);
    int dst = a * 256 + ((q * 8) ^ ((a & 7) << 4));
    *(ushort4v*)(fswz + dst) = u;
  } else if (b < 1600) {
    __shared__ float part[2][128];
    const int idx = b - 1280;          // [0,320)
    const int c = idx >> 4, grp = idx & 15;
    const int d = threadIdx.x & 127, half = threadIdx.x >> 7;
    const int i0 = grp * 32 + half * 16;
    float s = 0.f;
#pragma unroll
    for (int k = 0; k < 16; ++k) {     // 16 independent load pairs (latency-hidden)
      int i = i0 + k;
      s += (float)labels[i * NL + c] * feat[(size_t)i * (NL * 128) + c * 128 + d];
    }
    part[half][d] = s;
    __syncthreads();
    if (half == 0) gp[(c * 16 + grp) * 128 + d] = part[0][d] + part[1][d];
  } else {
    const int idx = b - 1600;          // [0,1600): zero 6.55 MB of Pm
    uint4v z = {0u, 0u, 0u, 0u};
    *(uint4v*)((unsigned char*)Pm + ((size_t)idx * 256 + threadIdx.x) * 16) = z;
  }
}

// Units: for class l, 16 strips s, classes c in [l,20). 3360 blocks x 64 thr.
__global__ __launch_bounds__(64) void k_gram(const unsigned char* __restrict__ fswz,
                                             float* __restrict__ Pr,
                                             unsigned short* __restrict__ Pm) {
  __shared__ unsigned char lds[12288];   // three 4KB slice buffers
  int u = blockIdx.x, l = 0;
  while (u >= 16 * (20 - l)) { u -= 16 * (20 - l); ++l; }
  const int s = u & 15;
  const int c = l + (u >> 4);
  const int R = l * 16 + s;              // 32-row strip, rows [32R, 32R+32)
  const int t0 = (c == l) ? 2 * s : 0;   // first slice (within class c's 32)
  const int lane = threadIdx.x;
  const int fr = lane & 15, kg = lane >> 4;
  const int xr = (fr & 7) << 4;

  // ---- persistent A fragments: 8 x short8 = 32 VGPR ----
  short8 af[4][2];   // [kk][m]
#pragma unroll
  for (int kk = 0; kk < 4; ++kk)
#pragma unroll
    for (int m = 0; m < 2; ++m)
      af[kk][m] = *(const short8*)(fswz + (size_t)(R * 32 + m * 16 + fr) * 256 +
                                   ((kk * 64 + kg * 16) ^ xr));

  const unsigned char* gB = fswz + (size_t)c * 512 * 256 + lane * 16;
  auto stage = [&](int buf, int t) {     // slice t: 16 Gram-cols = 4KB
    const unsigned char* g = gB + t * 4096;
    unsigned char* lb = lds + buf * 4096 + lane * 16;
#pragma unroll
    for (int p = 0; p < 4; ++p)
      __builtin_amdgcn_global_load_lds(
          (const __attribute__((address_space(1))) unsigned int*)(g + p * 1024),
          (__attribute__((address_space(3))) unsigned int*)(lb + p * 1024), 16, 0, 0);
  };

  stage(0, t0);
  stage(1, t0 + 1);                      // t0 <= 30, so t0+1 <= 31 valid
  float esum[2][4] = {};
  int bi = 0;

  for (int t = t0; t < 32; ++t) {
    asm volatile("" ::: "memory");
    if (t + 2 < 32) {
      int nb = bi + 2; if (nb >= 3) nb -= 3;
      stage(nb, t + 2);
      asm volatile("s_waitcnt vmcnt(8)" ::: "memory");   // slice t resident
    } else if (t + 1 < 32) {
      asm volatile("s_waitcnt vmcnt(4)" ::: "memory");
    } else {
      asm volatile("s_waitcnt vmcnt(0)" ::: "memory");
    }

    const unsigned char* lb = lds + bi * 4096;
    f32x4 acc[2] = {};                   // 32 rows x 16 cols
#pragma unroll
    for (int kk = 0; kk < 4; ++kk) {
      short8 bf = *(const short8*)(lb + fr * 256 + ((kk * 64 + kg * 16) ^ xr));
#pragma unroll
      for (int m = 0; m < 2; ++m)
        acc[m] = __builtin_amdgcn_mfma_f32_16x16x32_bf16(af[kk][m], bf, acc[m], 0, 0, 0);
    }

    if (c == l && t < 2 * s + 2) {
      // diagonal-overlap slice: full block computed, mask i==j, row-credit only
      const int uv = t - 2 * s;
#pragma unroll
      for (int m = 0; m < 2; ++m)
#pragma unroll
        for (int reg = 0; reg < 4; ++reg) {
          float ex = fexp2(acc[m][reg]);
          if (m == uv && (kg * 4 + reg) == fr) ex = 0.f;
          esum[m][reg] += ex;
        }
    } else {
      // strictly-above slice: row credit + mirror col credit
      float cs = 0.f;
#pragma unroll
      for (int m = 0; m < 2; ++m)
#pragma unroll
        for (int reg = 0; reg < 4; ++reg) {
          float ex = fexp2(acc[m][reg]);
          esum[m][reg] += ex;
          cs += ex;
        }
      cs += __shfl_xor(cs, 16, 64);
      cs += __shfl_xor(cs, 32, 64);      // col-sum over the strip's 32 rows
      if (lane < 16)                     // kg==0 lanes, col = fr
        Pm[(size_t)(l * 16 + s) * 10240 + c * 512 + t * 16 + fr] = f2bf(cs);
    }
    if (++bi == 3) bi = 0;
  }

  // ---- unit flush: reduce esum over fr + plain stores ----
#pragma unroll
  for (int m = 0; m < 2; ++m)
#pragma unroll
    for (int reg = 0; reg < 4; ++reg) {
      float e = esum[m][reg];
      e += __shfl_xor(e, 1, 64); e += __shfl_xor(e, 2, 64);
      e += __shfl_xor(e, 4, 64); e += __shfl_xor(e, 8, 64);
      if (fr == 0)
        Pr[(R * 20 + c) * 32 + m * 16 + kg * 4 + reg] = e;
    }
}

// Blocks [0,2560): wnum (wave per (c,i), folds 16 gp partials, coalesced).
// Blocks [2560,2600): Slog = log( triangle row parts + 320 mirror parts ).
__global__ __launch_bounds__(256) void k_ws(const float* __restrict__ Pr,
                                            const unsigned short* __restrict__ Pm,
                                            const float* __restrict__ feat,
                                            const float* __restrict__ gp,
                                            float* __restrict__ Slog,
                                            float* __restrict__ wnum) {
  const int b = blockIdx.x;
  if (b < 2560) {
    const int lane = threadIdx.x & 63;
    const int p = b * 4 + (threadIdx.x >> 6);   // pair c*512+i
    const int c = p >> 9, i = p & 511;
    float2 f = *(const float2*)(feat + (size_t)i * (NL * 128) + c * 128 + lane * 2);
    float gx = 0.f, gy = 0.f;
#pragma unroll
    for (int q = 0; q < 16; ++q) {
      float2 g2 = *(const float2*)(gp + (c * 16 + q) * 128 + lane * 2);
      gx += g2.x; gy += g2.y;
    }
    float v = f.x * gx + f.y * gy;
#pragma unroll
    for (int sh = 1; sh < 64; sh <<= 1) v += __shfl_xor(v, sh, 64);
    if (lane == 0) wnum[p] = (v - 1.f) * TEMP_INV;   // self term f.f==1 removed
  } else {
    int idx = (b - 2560) * 256 + threadIdx.x;   // [0, 10240)
    int c = idx >> 9, i = idx & 511;
    float ssum = 0.f;
#pragma unroll
    for (int l2 = 0; l2 < NL; ++l2)
      if (c >= l2)   // triangle row-credit exists only for c >= row class
        ssum += Pr[(((l2 * 16) + (i >> 5)) * 20 + c) * 32 + (i & 31)];
#pragma unroll 4
    for (int s = 0; s < 16; ++s)
#pragma unroll
      for (int l2 = 0; l2 < NL; ++l2)
        ssum += bf2f(Pm[(size_t)(c * 16 + s) * 10240 + l2 * 512 + i]);
    Slog[idx] = logf(ssum);
  }
}

// Per-anchor combine + mean. One block, 512 threads.
__global__ __launch_bounds__(512) void k_final(const float* __restrict__ Slog,
                                               const float* __restrict__ wnum,
                                               const int* __restrict__ labels,
                                               float* __restrict__ out) {
  __shared__ float cnt[NL];
  __shared__ float red[8];
  const int i = threadIdx.x;
  if (i < NL) cnt[i] = 0.f;
  __syncthreads();
  int lab[NL];
#pragma unroll
  for (int cI = 0; cI < NL; ++cI) lab[cI] = labels[i * NL + cI];
#pragma unroll
  for (int cI = 0; cI < NL; ++cI)
    if (lab[cI]) atomicAdd(&cnt[cI], 1.f);
  __syncthreads();
  float avg = 0.f, acc = 0.f;
#pragma unroll
  for (int cI = 0; cI < NL; ++cI) {
    if (lab[cI]) {
      float wgt = cnt[cI] - 1.f;
      avg += wgt;
      acc += wnum[cI * NB + i] - wgt * Slog[cI * NB + i];
    }
  }
  float v = acc / (avg == 0.f ? 1.f : avg);
#pragma unroll
  for (int s = 1; s < 64; s <<= 1) v += __shfl_xor(v, s, 64);
  if ((i & 63) == 0) red[i >> 6] = v;
  __syncthreads();
  if (i == 0) {
    float tot = 0.f;
#pragma unroll
    for (int k = 0; k < 8; ++k) tot += red[k];
    out[0] = -(tot / (float)NB);
  }
}

extern "C" void kernel_launch(void* const* d_in, const int* in_sizes, int n_in,
                              void* d_out, int out_size, void* d_ws, size_t ws_size,
                              hipStream_t stream) {
  const float* feat = (const float*)d_in[0];
  const int* labels = (const int*)d_in[1];
  float* out = (float*)d_out;
  unsigned char* ws = (unsigned char*)d_ws;
  unsigned char* fswz = ws;                              // 2,621,440 B
  unsigned short* Pm = (unsigned short*)(ws + FBYTES);   // 6,553,600 B (bf16)
  float* Pr = (float*)(ws + FBYTES + PM_ELEMS * 2);      // 819,200 B
  float* gp = Pr + 320 * 20 * 32;                        // 163,840 B
  float* Slog = gp + 320 * 128;                          // 40,960 B
  float* wnum = Slog + NROW;                             // 40,960 B

  k_prep<<<3200, 256, 0, stream>>>(feat, labels, fswz, gp, Pm);
  k_gram<<<3360, 64, 0, stream>>>(fswz, Pr, Pm);
  k_ws<<<2600, 256, 0, stream>>>(Pr, Pm, feat, gp, Slog, wnum);
  k_final<<<1, 512, 0, stream>>>(Slog, wnum, labels, out);
}

// Round 11
// 61.608 us; speedup vs baseline: 1.2389x; 1.2389x over previous
//
#include <hip/hip_runtime.h>

// NewSupConLoss: B=512, L=20, D=128. Full Gram N=10240, fused exp/rowsum.
// Round 11: R9 wave-granular barrier-free structure, occupancy-fixed.
// 6400 single-wave blocks (64-row strip x 256-col half-class), 16 slices of
// 16 cols, 2x4KB LDS (depth-1 prefetch, counted vmcnt) -> 20 blocks/CU
// (LDS cap) ~ 5 waves/SIMD. Diagonal mask branched to 4/16 slices.

#define NB 512
#define NL 20
#define NROW (NB * NL)            // 10240
#define FBYTES (NROW * 256)       // 2,621,440
#define SCALE 4.5398160f          // sqrt(log2(e)/0.07); dot feeds exp2 directly
#define TEMP_INV 14.285714285714286f

typedef float f32x4 __attribute__((ext_vector_type(4)));
typedef short short8 __attribute__((ext_vector_type(8)));
typedef unsigned short ushort4v __attribute__((ext_vector_type(4)));

static __device__ __forceinline__ unsigned short f2bf(float x) {
  unsigned int b = __float_as_uint(x);
  b += 0x7FFFu + ((b >> 16) & 1u);
  return (unsigned short)(b >> 16);
}

static __device__ __forceinline__ float fexp2(float x) {
#if __has_builtin(__builtin_amdgcn_exp2f)
  return __builtin_amdgcn_exp2f(x);
#else
  return exp2f(x);
#endif
}

// Blocks [0,1280): fp32 -> bf16 rows a=l*512+i, scaled, XOR-swizzled.
// Blocks [1280,1600): gp[c][grp][d] partial g-sums (16 independent loads).
__global__ __launch_bounds__(256) void k_prep(const float* __restrict__ feat,
                                              const int* __restrict__ labels,
                                              unsigned char* __restrict__ fswz,
                                              float* __restrict__ gp) {
  const int b = blockIdx.x;
  if (b < 1280) {
    int t = b * 256 + threadIdx.x;   // [0, 327680)
    int q = t & 31;
    int a = t >> 5;
    int l = a >> 9;
    int i = a & 511;
    const float* src = feat + (size_t)i * (NL * 128) + l * 128 + q * 4;
    float4 v = *(const float4*)src;
    ushort4v u;
    u.x = f2bf(v.x * SCALE); u.y = f2bf(v.y * SCALE);
    u.z = f2bf(v.z * SCALE); u.w = f2bf(v.w * SCALE);
    int dst = a * 256 + ((q * 8) ^ ((a & 7) << 4));
    *(ushort4v*)(fswz + dst) = u;
  } else {
    __shared__ float part[2][128];
    const int idx = b - 1280;          // [0,320)
    const int c = idx >> 4, grp = idx & 15;
    const int d = threadIdx.x & 127, half = threadIdx.x >> 7;
    const int i0 = grp * 32 + half * 16;
    float s = 0.f;
#pragma unroll
    for (int k = 0; k < 16; ++k) {     // independent load pairs, latency-hidden
      int i = i0 + k;
      s += (float)labels[i * NL + c] * feat[(size_t)i * (NL * 128) + c * 128 + d];
    }
    part[half][d] = s;
    __syncthreads();
    if (half == 0) gp[(c * 16 + grp) * 128 + d] = part[0][d] + part[1][d];
  }
}

// Pr[c][h][sr][r] : partial row-sums of exp over 256 cols (class c, half h).
// Grid (320 = sr*2+h, 20 c), 64 threads (1 wave).
__global__ __launch_bounds__(64) void k_gram(const unsigned char* __restrict__ fswz,
                                             float* __restrict__ Pr) {
  __shared__ unsigned char lds[8192];    // two wave-private 4KB slice buffers
  const int x = blockIdx.x;              // [0,320)
  const int h = x & 1, sr = x >> 1;      // col half, 64-row strip [sr*64,+64)
  const int c = blockIdx.y;              // class: cols [c*512 + h*256, +256)
  const int lane = threadIdx.x;          // 0..63
  const int fr = lane & 15, kg = lane >> 4;
  const int xr = (fr & 7) << 4;

  // ---- persistent A fragments: 16 x short8 = 64 VGPR ----
  short8 af[4][4];   // [kk][m]
#pragma unroll
  for (int kk = 0; kk < 4; ++kk)
#pragma unroll
    for (int m = 0; m < 4; ++m)
      af[kk][m] = *(const short8*)(fswz + (size_t)(sr * 64 + m * 16 + fr) * 256 +
                                   ((kk * 64 + kg * 16) ^ xr));

  const unsigned char* gB = fswz + ((size_t)c * 512 + h * 256) * 256 + lane * 16;
  auto stage = [&](int buf, int t) {     // slice t: 16 Gram-cols = 4KB
    const unsigned char* g = gB + t * 4096;
    unsigned char* lb = lds + buf * 4096 + lane * 16;
#pragma unroll
    for (int p = 0; p < 4; ++p)
      __builtin_amdgcn_global_load_lds(
          (const __attribute__((address_space(1))) unsigned int*)(g + p * 1024),
          (__attribute__((address_space(3))) unsigned int*)(lb + p * 1024), 16, 0, 0);
  };

  stage(0, 0);
  float esum[4][4] = {};   // [m][reg]

  // diagonal (i==j) lives in half (d8>>2), slices [td0, td0+4), d8 = sr&7
  const int d8 = sr & 7;
  const bool diagh = ((d8 >> 2) == h);
  const int td0 = (d8 & 3) * 4;

  for (int t = 0; t < 16; ++t) {
    asm volatile("" ::: "memory");   // keep stage below last iter's ds_reads
    if (t < 15) {
      stage((t + 1) & 1, t + 1);
      asm volatile("s_waitcnt vmcnt(4)" ::: "memory");   // slice t resident
    } else {
      asm volatile("s_waitcnt vmcnt(0)" ::: "memory");
    }

    const unsigned char* lb = lds + (t & 1) * 4096;
    f32x4 acc[4] = {};   // 64 rows x 16 cols
#pragma unroll
    for (int kk = 0; kk < 4; ++kk) {
      short8 bf = *(const short8*)(lb + fr * 256 + ((kk * 64 + kg * 16) ^ xr));
#pragma unroll
      for (int m = 0; m < 4; ++m)
        acc[m] = __builtin_amdgcn_mfma_f32_16x16x32_bf16(af[kk][m], bf, acc[m], 0, 0, 0);
    }

    // ---- epilogue: exp + accumulate; mask only on the 4 diag slices ----
    if (diagh && t >= td0 && t < td0 + 4) {
      const int mt = t - td0;
#pragma unroll
      for (int m = 0; m < 4; ++m)
#pragma unroll
        for (int reg = 0; reg < 4; ++reg) {
          float ex = fexp2(acc[m][reg]);
          if (m == mt && (kg * 4 + reg) == fr) ex = 0.f;
          esum[m][reg] += ex;
        }
    } else {
#pragma unroll
      for (int m = 0; m < 4; ++m)
#pragma unroll
        for (int reg = 0; reg < 4; ++reg)
          esum[m][reg] += fexp2(acc[m][reg]);
    }
  }

  // ---- flush once: reduce over fr (16 cols) + plain stores ----
#pragma unroll
  for (int m = 0; m < 4; ++m)
#pragma unroll
    for (int reg = 0; reg < 4; ++reg) {
      float e = esum[m][reg];
      e += __shfl_xor(e, 1, 64); e += __shfl_xor(e, 2, 64);
      e += __shfl_xor(e, 4, 64); e += __shfl_xor(e, 8, 64);
      if (fr == 0)
        Pr[(((size_t)c * 2 + h) * 160 + sr) * 64 + m * 16 + kg * 4 + reg] = e;
    }
}

// Blocks [0,2560): wnum (wave per (c,i), folds 16 gp partials, coalesced).
// Blocks [2560,2600): Slog = log(sum of 40 Pr partials), coalesced.
__global__ __launch_bounds__(256) void k_ws(const float* __restrict__ Pr,
                                            const float* __restrict__ feat,
                                            const float* __restrict__ gp,
                                            float* __restrict__ Slog,
                                            float* __restrict__ wnum) {
  const int b = blockIdx.x;
  if (b < 2560) {
    const int lane = threadIdx.x & 63;
    const int p = b * 4 + (threadIdx.x >> 6);   // pair c*512+i
    const int c = p >> 9, i = p & 511;
    float2 f = *(const float2*)(feat + (size_t)i * (NL * 128) + c * 128 + lane * 2);
    float gx = 0.f, gy = 0.f;
#pragma unroll
    for (int q = 0; q < 16; ++q) {
      float2 g2 = *(const float2*)(gp + (c * 16 + q) * 128 + lane * 2);
      gx += g2.x; gy += g2.y;
    }
    float v = f.x * gx + f.y * gy;
#pragma unroll
    for (int sh = 1; sh < 64; sh <<= 1) v += __shfl_xor(v, sh, 64);
    if (lane == 0) wnum[p] = (v - 1.f) * TEMP_INV;   // self term f.f==1 removed
  } else {
    int idx = (b - 2560) * 256 + threadIdx.x;   // [0, 10240)
    int c = idx >> 9, i = idx & 511;
    float s = 0.f;
#pragma unroll
    for (int l2 = 0; l2 < NL; ++l2) {
      const float* p2 = Pr + (((size_t)c * 2) * 160 + l2 * 8 + (i >> 6)) * 64 + (i & 63);
      s += p2[0] + p2[160 * 64];
    }
    Slog[idx] = logf(s);
  }
}

// Per-anchor combine + mean. One block, 512 threads.
__global__ __launch_bounds__(512) void k_final(const float* __restrict__ Slog,
                                               const float* __restrict__ wnum,
                                               const int* __restrict__ labels,
                                               float* __restrict__ out) {
  __shared__ float cnt[NL];
  __shared__ float red[8];
  const int i = threadIdx.x;
  if (i < NL) cnt[i] = 0.f;
  __syncthreads();
  int lab[NL];
#pragma unroll
  for (int cI = 0; cI < NL; ++cI) lab[cI] = labels[i * NL + cI];
#pragma unroll
  for (int cI = 0; cI < NL; ++cI)
    if (lab[cI]) atomicAdd(&cnt[cI], 1.f);
  __syncthreads();
  float avg = 0.f, acc = 0.f;
#pragma unroll
  for (int cI = 0; cI < NL; ++cI) {
    if (lab[cI]) {
      float wgt = cnt[cI] - 1.f;
      avg += wgt;
      acc += wnum[cI * NB + i] - wgt * Slog[cI * NB + i];
    }
  }
  float v = acc / (avg == 0.f ? 1.f : avg);
#pragma unroll
  for (int s = 1; s < 64; s <<= 1) v += __shfl_xor(v, s, 64);
  if ((i & 63) == 0) red[i >> 6] = v;
  __syncthreads();
  if (i == 0) {
    float tot = 0.f;
#pragma unroll
    for (int k = 0; k < 8; ++k) tot += red[k];
    out[0] = -(tot / (float)NB);
  }
}

extern "C" void kernel_launch(void* const* d_in, const int* in_sizes, int n_in,
                              void* d_out, int out_size, void* d_ws, size_t ws_size,
                              hipStream_t stream) {
  const float* feat = (const float*)d_in[0];
  const int* labels = (const int*)d_in[1];
  float* out = (float*)d_out;
  unsigned char* ws = (unsigned char*)d_ws;
  unsigned char* fswz = ws;                          // 2,621,440 B
  float* Pr = (float*)(ws + FBYTES);                 // 20*2*160*64 f32 = 1.6 MB
  float* gp = Pr + 20 * 2 * 160 * 64;                // 320*128 f32
  float* Slog = gp + 320 * 128;                      // 10240 f32
  float* wnum = Slog + NROW;                         // 10240 f32

  k_prep<<<1600, 256, 0, stream>>>(feat, labels, fswz, gp);
  dim3 grid(320, 20);
  k_gram<<<grid, 64, 0, stream>>>(fswz, Pr);
  k_ws<<<2600, 256, 0, stream>>>(Pr, feat, gp, Slog, wnum);
  k_final<<<1, 512, 0, stream>>>(Slog, wnum, labels, out);
}